// Round 5
// baseline (242.091 us; speedup 1.0000x reference)
//
#include <hip/hip_runtime.h>

#define B_  4
#define N_  4096   // H*W
#define C_  256
#define D_  32

typedef __attribute__((ext_vector_type(8))) short bf8;   // 8 bf16 (4 VGPRs)
typedef __attribute__((ext_vector_type(4))) float f4;    // MFMA C/D frag

__device__ __forceinline__ unsigned short bft(float f) {
    unsigned u = __builtin_bit_cast(unsigned, f);
    return (unsigned short)((u + 0x8000u) >> 16);
}
// pack two floats to bf16x2 (a->low, b->high)
__device__ __forceinline__ unsigned pk2(float a, float b) {
    unsigned ua = __builtin_bit_cast(unsigned, a) + 0x8000u;
    unsigned ub = __builtin_bit_cast(unsigned, b) + 0x8000u;
    return __builtin_amdgcn_perm(ub, ua, 0x07060302u);
}

// ---------------------------------------------------------------------------
// prep: weights -> bf16. Wqkb[64][256] = Wq rows 0-31, Wk rows 32-63.
// ---------------------------------------------------------------------------
__global__ __launch_bounds__(256) void prep(
    const float* __restrict__ Wq, const float* __restrict__ Wk,
    const float* __restrict__ Wv,
    unsigned short* __restrict__ Wqkb, unsigned short* __restrict__ Wvb)
{
    int i = blockIdx.x * 256 + threadIdx.x;
    if (i < 8192)       Wqkb[i] = bft(Wq[i]);
    else if (i < 16384) Wqkb[i] = bft(Wk[i - 8192]);
    Wvb[i] = bft(Wv[i]);
}

// ---------------------------------------------------------------------------
// qkv v2: n-tile 64 per block (4x weight amortization vs R4), 512 thr, 8 waves.
// wave role: vr = w&3 (row strip: qk rows vr*16, v rows vr*64), nh = w>>2
// (n-frags {2nh, 2nh+1}). Weight L2 traffic: 320 KB/block x 256 blocks = 82 MB.
// q pre-scaled by log2(e). Outputs: qb,kb [B][N][32]; vb [B][C][N].
// ---------------------------------------------------------------------------
__global__ __launch_bounds__(512) void qkv(
    const float* __restrict__ x,
    const unsigned short* __restrict__ Wqkb, const unsigned short* __restrict__ Wvb,
    const float* __restrict__ bq, const float* __restrict__ bk,
    const float* __restrict__ bv,
    unsigned short* __restrict__ qb, unsigned short* __restrict__ kb,
    unsigned short* __restrict__ vb)
{
    const int b = blockIdx.y, n0 = blockIdx.x * 64;
    const int t = threadIdx.x;
    const int lane = t & 63, w = t >> 6, c15 = lane & 15, g = lane >> 4;
    const int vr = w & 3, nh = w >> 2;

    __shared__ __align__(16) unsigned short xs[64][264];   // n x c, 528-B rows

    // coalesced stage + transpose: idx -> (c = idx>>4, 4-float chunk q)
    #pragma unroll
    for (int it = 0; it < 8; ++it) {
        int idx = t + 512 * it;            // 0..4095
        int c = idx >> 4, q = idx & 15;
        float4 v = *(const float4*)(x + ((size_t)(b * C_ + c)) * N_ + n0 + q * 4);
        xs[q * 4 + 0][c] = bft(v.x);
        xs[q * 4 + 1][c] = bft(v.y);
        xs[q * 4 + 2][c] = bft(v.z);
        xs[q * 4 + 3][c] = bft(v.w);
    }
    __syncthreads();

    f4 qkacc[2]; f4 vacc[2][4];
    const f4 fz = {0.f, 0.f, 0.f, 0.f};
    qkacc[0] = fz; qkacc[1] = fz;
    #pragma unroll
    for (int nt = 0; nt < 2; ++nt)
        #pragma unroll
        for (int ct = 0; ct < 4; ++ct) vacc[nt][ct] = fz;

    const unsigned short* wqk = Wqkb + (vr * 16 + c15) * C_ + g * 8;
    const unsigned short* wv0 = Wvb + (vr * 64 + c15) * C_ + g * 8;
    const unsigned short* xsp = &xs[nh * 32 + c15][g * 8];

    #pragma unroll
    for (int ks = 0; ks < 8; ++ks) {
        bf8 xf0 = *(const bf8*)(xsp + ks * 32);              // n-frag 2nh
        bf8 xf1 = *(const bf8*)(xsp + 16 * 264 + ks * 32);   // n-frag 2nh+1
        bf8 af  = *(const bf8*)(wqk + ks * 32);
        qkacc[0] = __builtin_amdgcn_mfma_f32_16x16x32_bf16(af, xf0, qkacc[0], 0, 0, 0);
        qkacc[1] = __builtin_amdgcn_mfma_f32_16x16x32_bf16(af, xf1, qkacc[1], 0, 0, 0);
        #pragma unroll
        for (int ct = 0; ct < 4; ++ct) {
            bf8 bfv = *(const bf8*)(wv0 + ct * 16 * C_ + ks * 32);
            vacc[0][ct] = __builtin_amdgcn_mfma_f32_16x16x32_bf16(xf0, bfv, vacc[0][ct], 0, 0, 0);
            vacc[1][ct] = __builtin_amdgcn_mfma_f32_16x16x32_bf16(xf1, bfv, vacc[1][ct], 0, 0, 0);
        }
    }

    // epilogue q/k
    {
        float4 bias = (vr < 2) ? *(const float4*)(bq + (vr & 1) * 16 + 4 * g)
                               : *(const float4*)(bk + (vr & 1) * 16 + 4 * g);
        float sc = (vr < 2) ? 1.44269504f : 1.0f;
        unsigned short* base = (vr < 2) ? qb : kb;
        int d0 = (vr & 1) * 16 + 4 * g;
        #pragma unroll
        for (int nt = 0; nt < 2; ++nt) {
            int n = n0 + (nh * 2 + nt) * 16 + c15;
            f4 a = qkacc[nt];
            uint2 pk;
            pk.x = pk2((a.x + bias.x) * sc, (a.y + bias.y) * sc);
            pk.y = pk2((a.z + bias.z) * sc, (a.w + bias.w) * sc);
            *(uint2*)(base + ((size_t)(b * N_ + n)) * D_ + d0) = pk;
        }
    }
    // epilogue v
    #pragma unroll
    for (int ct = 0; ct < 4; ++ct) {
        int cout = vr * 64 + ct * 16 + c15;
        float bvv = bv[cout];
        #pragma unroll
        for (int nt = 0; nt < 2; ++nt) {
            f4 a = vacc[nt][ct];
            uint2 pk;
            pk.x = pk2(a.x + bvv, a.y + bvv);
            pk.y = pk2(a.z + bvv, a.w + bvv);
            *(uint2*)(vb + ((size_t)(b * C_ + cout)) * (size_t)N_
                      + n0 + (nh * 2 + nt) * 16 + 4 * g) = pk;
        }
    }
}

// ---------------------------------------------------------------------------
// attn v2: M=128 queries, c-half 128, KT=128, 1024 thr = 16 waves = 4/SIMD.
// produce: wave (pm=w&7 -> m-frag, pnh=w>>3 -> n-frags pnh*4..+3), 4 S-frags.
// consume: wave (mq=w&3 -> m-frags {2mq,2mq+1}, cq=(w>>2)&1 -> c-frags,
// ksh=w>>3 -> key-half); acc[2][4]; ks-halves combined via LDS at end.
// Light lgkmcnt barrier keeps K/V prefetch in flight.
// ---------------------------------------------------------------------------
__global__ __launch_bounds__(1024, 4) void attn(
    const unsigned short* __restrict__ qb, const unsigned short* __restrict__ kb,
    const unsigned short* __restrict__ vb, const float* __restrict__ x,
    const float* __restrict__ gamma, float* __restrict__ out)
{
    const int b = blockIdx.z, c0 = blockIdx.y * 128, m0 = blockIdx.x * 128;
    const int t = threadIdx.x;
    const int lane = t & 63, w = t >> 6, c15 = lane & 15, g = lane >> 4;
    const int pm = w & 7, pnh = w >> 3;                  // produce role
    const int mq = w & 3, cq = (w >> 2) & 1, ksh = w >> 3; // consume role

    __shared__ __align__(16) unsigned short Ps[2][128][136]; // 272-B rows
    __shared__ float l_s[2][128];

    const f4 fz = {0.f, 0.f, 0.f, 0.f};

    bf8 qf = *(const bf8*)(qb + ((size_t)(b * N_ + m0 + pm * 16 + c15)) * D_ + g * 8);

    const unsigned short* kptr = kb + ((size_t)(b * N_ + pnh * 64 + c15)) * D_ + g * 8;
    bf8 kf[4];
    #pragma unroll
    for (int ff = 0; ff < 4; ++ff)
        kf[ff] = *(const bf8*)(kptr + (size_t)ff * 16 * D_);
    kptr += (size_t)128 * D_;

    f4 acc[2][4];
    #pragma unroll
    for (int mi = 0; mi < 2; ++mi)
        #pragma unroll
        for (int ct = 0; ct < 4; ++ct) acc[mi][ct] = fz;
    float lrun = 0.f;

    const unsigned short* vptr = vb + ((size_t)(b * C_ + c0 + cq * 64)) * (size_t)N_
                                 + ksh * 64 + g * 8;

    for (int it = 0; it < 32; ++it) {
        const int buf = it & 1;
        // V for this iter (in flight across produce + barrier)
        bf8 vf[2][4];
        #pragma unroll
        for (int ki = 0; ki < 2; ++ki)
            #pragma unroll
            for (int ct = 0; ct < 4; ++ct)
                vf[ki][ct] = *(const bf8*)(vptr + (size_t)(ct * 16 + c15) * N_ + ki * 32);
        // produce S^T = K·Q^T
        f4 s[4];
        #pragma unroll
        for (int ff = 0; ff < 4; ++ff)
            s[ff] = __builtin_amdgcn_mfma_f32_16x16x32_bf16(kf[ff], qf, fz, 0, 0, 0);
        // K prefetch for next iter
        if (it < 31) {
            #pragma unroll
            for (int ff = 0; ff < 4; ++ff)
                kf[ff] = *(const bf8*)(kptr + (size_t)ff * 16 * D_);
            kptr += (size_t)128 * D_;
        }
        // exp2 (q pre-scaled), pack, write P
        #pragma unroll
        for (int ff = 0; ff < 4; ++ff) {
            float p0 = __builtin_amdgcn_exp2f(s[ff].x);
            float p1 = __builtin_amdgcn_exp2f(s[ff].y);
            float p2 = __builtin_amdgcn_exp2f(s[ff].z);
            float p3 = __builtin_amdgcn_exp2f(s[ff].w);
            lrun += (p0 + p1) + (p2 + p3);
            uint2 pk; pk.x = pk2(p0, p1); pk.y = pk2(p2, p3);
            *(uint2*)&Ps[buf][pm * 16 + c15][(pnh * 4 + ff) * 16 + 4 * g] = pk;
        }
        // light barrier: drain LDS only; global loads stay in flight
        asm volatile("s_waitcnt lgkmcnt(0)\n\ts_barrier" ::: "memory");
        // consume: O += P·V^T (this wave's 32m x 64c tile, key-half ksh)
        #pragma unroll
        for (int ki = 0; ki < 2; ++ki) {
            const int kcol = ksh * 64 + ki * 32 + g * 8;
            bf8 pf0 = *(const bf8*)&Ps[buf][(2 * mq + 0) * 16 + c15][kcol];
            bf8 pf1 = *(const bf8*)&Ps[buf][(2 * mq + 1) * 16 + c15][kcol];
            #pragma unroll
            for (int ct = 0; ct < 4; ++ct) {
                acc[0][ct] = __builtin_amdgcn_mfma_f32_16x16x32_bf16(pf0, vf[ki][ct], acc[0][ct], 0, 0, 0);
                acc[1][ct] = __builtin_amdgcn_mfma_f32_16x16x32_bf16(pf1, vf[ki][ct], acc[1][ct], 0, 0, 0);
            }
        }
        vptr += 128;
    }

    // l: finish per-m sums (reduce over g), publish per n-half
    lrun += __shfl_xor(lrun, 16);
    lrun += __shfl_xor(lrun, 32);
    if (lane < 16) l_s[pnh][pm * 16 + lane] = lrun;
    __syncthreads();   // also: all Ps reads done before reuse below

    float* accs = (float*)&Ps[0][0][0];  // 64 KB reuse for ks-combine
    if (ksh == 1) {
        #pragma unroll
        for (int mi = 0; mi < 2; ++mi)
            #pragma unroll
            for (int ct = 0; ct < 4; ++ct)
                *(f4*)&accs[(((w & 7) * 8 + mi * 4 + ct) * 64 + lane) * 4] = acc[mi][ct];
    }
    __syncthreads();
    if (ksh == 0) {
        const float g0 = gamma[0];
        #pragma unroll
        for (int mi = 0; mi < 2; ++mi) {
            const int mrow = (2 * mq + mi) * 16;
            float4 la = *(const float4*)&l_s[0][mrow + 4 * g];
            float4 lb = *(const float4*)&l_s[1][mrow + 4 * g];
            float i0 = 1.f / (la.x + lb.x), i1 = 1.f / (la.y + lb.y);
            float i2 = 1.f / (la.z + lb.z), i3 = 1.f / (la.w + lb.w);
            #pragma unroll
            for (int ct = 0; ct < 4; ++ct) {
                f4 o = *(const f4*)&accs[((w * 8 + mi * 4 + ct) * 64 + lane) * 4];
                f4 a = acc[mi][ct];
                int c = c0 + (cq * 4 + ct) * 16 + c15;
                size_t base = ((size_t)(b * C_ + c)) * (size_t)N_ + m0 + mrow + 4 * g;
                float4 xv = *(const float4*)(x + base);
                float4 r;
                r.x = g0 * ((a.x + o.x) * i0) + xv.x;
                r.y = g0 * ((a.y + o.y) * i1) + xv.y;
                r.z = g0 * ((a.z + o.z) * i2) + xv.z;
                r.w = g0 * ((a.w + o.w) * i3) + xv.w;
                *(float4*)(out + base) = r;
            }
        }
    }
}

extern "C" void kernel_launch(void* const* d_in, const int* in_sizes, int n_in,
                              void* d_out, int out_size, void* d_ws, size_t ws_size,
                              hipStream_t stream) {
    const float* x     = (const float*)d_in[0];
    const float* Wq    = (const float*)d_in[1];
    const float* bq    = (const float*)d_in[2];
    const float* Wk    = (const float*)d_in[3];
    const float* bk    = (const float*)d_in[4];
    const float* Wv    = (const float*)d_in[5];
    const float* bv    = (const float*)d_in[6];
    const float* gamma = (const float*)d_in[7];
    float* out = (float*)d_out;

    unsigned short* qb   = (unsigned short*)d_ws;
    unsigned short* kb   = qb + (size_t)B_ * N_ * D_;
    unsigned short* vb   = kb + (size_t)B_ * N_ * D_;
    unsigned short* Wqkb = vb + (size_t)B_ * C_ * N_;
    unsigned short* Wvb  = Wqkb + 64 * C_;

    prep<<<256, 256, 0, stream>>>(Wq, Wk, Wv, Wqkb, Wvb);
    qkv<<<dim3(64, 4), 512, 0, stream>>>(x, Wqkb, Wvb, bq, bk, bv, qb, kb, vb);
    attn<<<dim3(32, 2, 4), 1024, 0, stream>>>(qb, kb, vb, x, gamma, out);
}

// Round 6
// 239.526 us; speedup vs baseline: 1.0107x; 1.0107x over previous
//
#include <hip/hip_runtime.h>

#define B_  4
#define N_  4096   // H*W
#define C_  256
#define D_  32

typedef __attribute__((ext_vector_type(8))) short bf8;   // 8 bf16 (4 VGPRs)
typedef __attribute__((ext_vector_type(4))) float f4;    // MFMA C/D frag

__device__ __forceinline__ unsigned short bft(float f) {
    unsigned u = __builtin_bit_cast(unsigned, f);
    return (unsigned short)((u + 0x8000u) >> 16);
}
// pack two floats to bf16x2 (a->low, b->high)
__device__ __forceinline__ unsigned pk2(float a, float b) {
    unsigned ua = __builtin_bit_cast(unsigned, a) + 0x8000u;
    unsigned ub = __builtin_bit_cast(unsigned, b) + 0x8000u;
    return __builtin_amdgcn_perm(ub, ua, 0x07060302u);
}

// ---------------------------------------------------------------------------
// prep: weights -> bf16. Wqkb[64][256] = Wq rows 0-31, Wk rows 32-63.
// ---------------------------------------------------------------------------
__global__ __launch_bounds__(256) void prep(
    const float* __restrict__ Wq, const float* __restrict__ Wk,
    const float* __restrict__ Wv,
    unsigned short* __restrict__ Wqkb, unsigned short* __restrict__ Wvb)
{
    int i = blockIdx.x * 256 + threadIdx.x;
    if (i < 8192)       Wqkb[i] = bft(Wq[i]);
    else if (i < 16384) Wqkb[i] = bft(Wk[i - 8192]);
    Wvb[i] = bft(Wv[i]);
}

// ---------------------------------------------------------------------------
// qkv: n-tile 64 per block, 512 thr, 8 waves (unchanged from R5 — measured
// equivalent; residual time is harness-side).  q pre-scaled by log2(e).
// ---------------------------------------------------------------------------
__global__ __launch_bounds__(512) void qkv(
    const float* __restrict__ x,
    const unsigned short* __restrict__ Wqkb, const unsigned short* __restrict__ Wvb,
    const float* __restrict__ bq, const float* __restrict__ bk,
    const float* __restrict__ bv,
    unsigned short* __restrict__ qb, unsigned short* __restrict__ kb,
    unsigned short* __restrict__ vb)
{
    const int b = blockIdx.y, n0 = blockIdx.x * 64;
    const int t = threadIdx.x;
    const int lane = t & 63, w = t >> 6, c15 = lane & 15, g = lane >> 4;
    const int vr = w & 3, nh = w >> 2;

    __shared__ __align__(16) unsigned short xs[64][264];

    #pragma unroll
    for (int it = 0; it < 8; ++it) {
        int idx = t + 512 * it;
        int c = idx >> 4, q = idx & 15;
        float4 v = *(const float4*)(x + ((size_t)(b * C_ + c)) * N_ + n0 + q * 4);
        xs[q * 4 + 0][c] = bft(v.x);
        xs[q * 4 + 1][c] = bft(v.y);
        xs[q * 4 + 2][c] = bft(v.z);
        xs[q * 4 + 3][c] = bft(v.w);
    }
    __syncthreads();

    f4 qkacc[2]; f4 vacc[2][4];
    const f4 fz = {0.f, 0.f, 0.f, 0.f};
    qkacc[0] = fz; qkacc[1] = fz;
    #pragma unroll
    for (int nt = 0; nt < 2; ++nt)
        #pragma unroll
        for (int ct = 0; ct < 4; ++ct) vacc[nt][ct] = fz;

    const unsigned short* wqk = Wqkb + (vr * 16 + c15) * C_ + g * 8;
    const unsigned short* wv0 = Wvb + (vr * 64 + c15) * C_ + g * 8;
    const unsigned short* xsp = &xs[nh * 32 + c15][g * 8];

    #pragma unroll
    for (int ks = 0; ks < 8; ++ks) {
        bf8 xf0 = *(const bf8*)(xsp + ks * 32);
        bf8 xf1 = *(const bf8*)(xsp + 16 * 264 + ks * 32);
        bf8 af  = *(const bf8*)(wqk + ks * 32);
        qkacc[0] = __builtin_amdgcn_mfma_f32_16x16x32_bf16(af, xf0, qkacc[0], 0, 0, 0);
        qkacc[1] = __builtin_amdgcn_mfma_f32_16x16x32_bf16(af, xf1, qkacc[1], 0, 0, 0);
        #pragma unroll
        for (int ct = 0; ct < 4; ++ct) {
            bf8 bfv = *(const bf8*)(wv0 + ct * 16 * C_ + ks * 32);
            vacc[0][ct] = __builtin_amdgcn_mfma_f32_16x16x32_bf16(xf0, bfv, vacc[0][ct], 0, 0, 0);
            vacc[1][ct] = __builtin_amdgcn_mfma_f32_16x16x32_bf16(xf1, bfv, vacc[1][ct], 0, 0, 0);
        }
    }

    {
        float4 bias = (vr < 2) ? *(const float4*)(bq + (vr & 1) * 16 + 4 * g)
                               : *(const float4*)(bk + (vr & 1) * 16 + 4 * g);
        float sc = (vr < 2) ? 1.44269504f : 1.0f;
        unsigned short* base = (vr < 2) ? qb : kb;
        int d0 = (vr & 1) * 16 + 4 * g;
        #pragma unroll
        for (int nt = 0; nt < 2; ++nt) {
            int n = n0 + (nh * 2 + nt) * 16 + c15;
            f4 a = qkacc[nt];
            uint2 pk;
            pk.x = pk2((a.x + bias.x) * sc, (a.y + bias.y) * sc);
            pk.y = pk2((a.z + bias.z) * sc, (a.w + bias.w) * sc);
            *(uint2*)(base + ((size_t)(b * N_ + n)) * D_ + d0) = pk;
        }
    }
    #pragma unroll
    for (int ct = 0; ct < 4; ++ct) {
        int cout = vr * 64 + ct * 16 + c15;
        float bvv = bv[cout];
        #pragma unroll
        for (int nt = 0; nt < 2; ++nt) {
            f4 a = vacc[nt][ct];
            uint2 pk;
            pk.x = pk2(a.x + bvv, a.y + bvv);
            pk.y = pk2(a.z + bvv, a.w + bvv);
            *(uint2*)(vb + ((size_t)(b * C_ + cout)) * (size_t)N_
                      + n0 + (nh * 2 + nt) * 16 + 4 * g) = pk;
        }
    }
}

// ---------------------------------------------------------------------------
// attn v3: M=64 queries, c-half 128, KT=128, 512 thr = 8 waves, grid
// (64,2,4)=512 blocks -> 2 blocks/CU co-resident (LDS 35 KB, VGPR<=128):
// one block's barrier drain overlaps the other's MFMA.
// produce: wave (pm=w&3 -> m-frag, pnh=w>>2 -> n-half, 4 frags).
// consume: wave (mh=w&1 -> m-frags {2mh,2mh+1}, cq=w>>1 -> c-frags
// {2cq,2cq+1}), full key range (no ks split, no end combine). acc[2][2].
// ---------------------------------------------------------------------------
__global__ __launch_bounds__(512, 4) void attn(
    const unsigned short* __restrict__ qb, const unsigned short* __restrict__ kb,
    const unsigned short* __restrict__ vb, const float* __restrict__ x,
    const float* __restrict__ gamma, float* __restrict__ out)
{
    const int b = blockIdx.z, c0 = blockIdx.y * 128, m0 = blockIdx.x * 64;
    const int t = threadIdx.x;
    const int lane = t & 63, w = t >> 6, c15 = lane & 15, g = lane >> 4;
    const int pm = w & 3, pnh = w >> 2;   // produce role
    const int mh = w & 1, cq = w >> 1;    // consume role

    __shared__ __align__(16) unsigned short Ps[2][64][136];  // 272-B rows
    __shared__ float l_s[2][64];

    const f4 fz = {0.f, 0.f, 0.f, 0.f};

    bf8 qf = *(const bf8*)(qb + ((size_t)(b * N_ + m0 + pm * 16 + c15)) * D_ + g * 8);

    const unsigned short* kptr = kb + ((size_t)(b * N_ + pnh * 64 + c15)) * D_ + g * 8;
    bf8 kf[4];
    #pragma unroll
    for (int ff = 0; ff < 4; ++ff)
        kf[ff] = *(const bf8*)(kptr + (size_t)ff * 16 * D_);
    kptr += (size_t)128 * D_;

    f4 acc[2][2];
    #pragma unroll
    for (int mi = 0; mi < 2; ++mi)
        #pragma unroll
        for (int ct = 0; ct < 2; ++ct) acc[mi][ct] = fz;
    float lrun = 0.f;

    const unsigned short* vptr = vb + ((size_t)(b * C_ + c0 + cq * 32)) * (size_t)N_ + g * 8;

    for (int it = 0; it < 32; ++it) {
        const int buf = it & 1;
        // V for this iter (in flight across produce + barrier)
        bf8 vf[4][2];
        #pragma unroll
        for (int ki = 0; ki < 4; ++ki)
            #pragma unroll
            for (int ct = 0; ct < 2; ++ct)
                vf[ki][ct] = *(const bf8*)(vptr + (size_t)(ct * 16 + c15) * N_ + ki * 32);
        // produce S^T = K·Q^T
        f4 s[4];
        #pragma unroll
        for (int ff = 0; ff < 4; ++ff)
            s[ff] = __builtin_amdgcn_mfma_f32_16x16x32_bf16(kf[ff], qf, fz, 0, 0, 0);
        // K prefetch for next iter
        if (it < 31) {
            #pragma unroll
            for (int ff = 0; ff < 4; ++ff)
                kf[ff] = *(const bf8*)(kptr + (size_t)ff * 16 * D_);
            kptr += (size_t)128 * D_;
        }
        // exp2 (q pre-scaled by log2e), pack, write P
        #pragma unroll
        for (int ff = 0; ff < 4; ++ff) {
            float p0 = __builtin_amdgcn_exp2f(s[ff].x);
            float p1 = __builtin_amdgcn_exp2f(s[ff].y);
            float p2 = __builtin_amdgcn_exp2f(s[ff].z);
            float p3 = __builtin_amdgcn_exp2f(s[ff].w);
            lrun += (p0 + p1) + (p2 + p3);
            uint2 pk; pk.x = pk2(p0, p1); pk.y = pk2(p2, p3);
            *(uint2*)&Ps[buf][pm * 16 + c15][(pnh * 4 + ff) * 16 + 4 * g] = pk;
        }
        // light barrier: drain LDS only; global loads stay in flight
        asm volatile("s_waitcnt lgkmcnt(0)\n\ts_barrier" ::: "memory");
        // consume: O += P·V^T (32m x 32c tile, all 128 keys)
        #pragma unroll
        for (int ki = 0; ki < 4; ++ki) {
            const int kcol = ki * 32 + g * 8;
            bf8 pf0 = *(const bf8*)&Ps[buf][(2 * mh + 0) * 16 + c15][kcol];
            bf8 pf1 = *(const bf8*)&Ps[buf][(2 * mh + 1) * 16 + c15][kcol];
            #pragma unroll
            for (int ct = 0; ct < 2; ++ct) {
                acc[0][ct] = __builtin_amdgcn_mfma_f32_16x16x32_bf16(pf0, vf[ki][ct], acc[0][ct], 0, 0, 0);
                acc[1][ct] = __builtin_amdgcn_mfma_f32_16x16x32_bf16(pf1, vf[ki][ct], acc[1][ct], 0, 0, 0);
            }
        }
        vptr += 128;
    }

    // l: finish per-m sums (reduce over g), publish per n-half
    lrun += __shfl_xor(lrun, 16);
    lrun += __shfl_xor(lrun, 32);
    if (lane < 16) l_s[pnh][pm * 16 + lane] = lrun;
    __syncthreads();

    const float g0 = gamma[0];
    #pragma unroll
    for (int mi = 0; mi < 2; ++mi) {
        const int mrow = (2 * mh + mi) * 16;
        float4 la = *(const float4*)&l_s[0][mrow + 4 * g];
        float4 lb = *(const float4*)&l_s[1][mrow + 4 * g];
        float i0 = 1.f / (la.x + lb.x), i1 = 1.f / (la.y + lb.y);
        float i2 = 1.f / (la.z + lb.z), i3 = 1.f / (la.w + lb.w);
        #pragma unroll
        for (int ct = 0; ct < 2; ++ct) {
            f4 a = acc[mi][ct];
            int c = c0 + (cq * 2 + ct) * 16 + c15;
            size_t base = ((size_t)(b * C_ + c)) * (size_t)N_ + m0 + mrow + 4 * g;
            float4 xv = *(const float4*)(x + base);
            float4 r;
            r.x = g0 * (a.x * i0) + xv.x;
            r.y = g0 * (a.y * i1) + xv.y;
            r.z = g0 * (a.z * i2) + xv.z;
            r.w = g0 * (a.w * i3) + xv.w;
            *(float4*)(out + base) = r;
        }
    }
}

extern "C" void kernel_launch(void* const* d_in, const int* in_sizes, int n_in,
                              void* d_out, int out_size, void* d_ws, size_t ws_size,
                              hipStream_t stream) {
    const float* x     = (const float*)d_in[0];
    const float* Wq    = (const float*)d_in[1];
    const float* bq    = (const float*)d_in[2];
    const float* Wk    = (const float*)d_in[3];
    const float* bk    = (const float*)d_in[4];
    const float* Wv    = (const float*)d_in[5];
    const float* bv    = (const float*)d_in[6];
    const float* gamma = (const float*)d_in[7];
    float* out = (float*)d_out;

    unsigned short* qb   = (unsigned short*)d_ws;
    unsigned short* kb   = qb + (size_t)B_ * N_ * D_;
    unsigned short* vb   = kb + (size_t)B_ * N_ * D_;
    unsigned short* Wqkb = vb + (size_t)B_ * C_ * N_;
    unsigned short* Wvb  = Wqkb + 64 * C_;

    prep<<<256, 256, 0, stream>>>(Wq, Wk, Wv, Wqkb, Wvb);
    qkv<<<dim3(64, 4), 512, 0, stream>>>(x, Wqkb, Wvb, bq, bk, bv, qb, kb, vb);
    attn<<<dim3(64, 2, 4), 512, 0, stream>>>(qb, kb, vb, x, gamma, out);
}